// Round 2
// 395.954 us; speedup vs baseline: 1.0026x; 1.0026x over previous
//
#include <hip/hip_runtime.h>
#include <stdint.h>

// ws layout (float offsets)
#define WS_HMUE 0          // [16][64][256] h_mean_ue (mean over p2 = row sums)
#define WS_HMAP 262144     // [16][64][256] h_mean_ap (mean over p1 = col sums)
#define WS_APM  524288     // [16][64] ap_mean
#define WS_UEM  525312     // [16][64] ue_mean
#define WS_Z    526336     // [2][16][64][256] pre-BN z (fp32), 524288 floats

// Kernel 1: H both-axis means (1024 blocks, one (b,d2) slice each) with the
// A_AP/A_UE row means folded in (2 rows per block).
__global__ __launch_bounds__(256) void k_reduce(
    const float* __restrict__ H,
    const float* __restrict__ A_AP, const float* __restrict__ A_UE,
    float* __restrict__ ws)
{
    const int bid  = blockIdx.x;
    const int tid  = threadIdx.x;
    const int w    = tid >> 6;     // wave 0..3
    const int lane = tid & 63;

    __shared__ float lds_row[256];
    __shared__ float lds_col[1024];   // [4 waves][256 cols]

    // slice rows = p1, cols = p2; row-major, row stride 256 floats
    const float4* Hs = (const float4*)(H + (size_t)bid * 65536);
    float c0 = 0.f, c1 = 0.f, c2 = 0.f, c3 = 0.f;
    const int b1 = lane & 1;
    const int b2 = lane & 2;

    // wave w handles rows it*16 + w*4 + {0..3}; batched 4-row butterfly:
    // 7 shuffles per 4 rows instead of 24.
    #pragma unroll 2
    for (int it = 0; it < 16; ++it) {
        const int rbase = it * 16 + w * 4;
        const float4 v0 = Hs[(rbase + 0) * 64 + lane];
        const float4 v1 = Hs[(rbase + 1) * 64 + lane];
        const float4 v2 = Hs[(rbase + 2) * 64 + lane];
        const float4 v3 = Hs[(rbase + 3) * 64 + lane];
        c0 += (v0.x + v1.x) + (v2.x + v3.x);
        c1 += (v0.y + v1.y) + (v2.y + v3.y);
        c2 += (v0.z + v1.z) + (v2.z + v3.z);
        c3 += (v0.w + v1.w) + (v2.w + v3.w);
        float rs0 = (v0.x + v0.y) + (v0.z + v0.w);
        float rs1 = (v1.x + v1.y) + (v1.z + v1.w);
        float rs2 = (v2.x + v2.y) + (v2.z + v2.w);
        float rs3 = (v3.x + v3.y) + (v3.z + v3.w);
        // stage 1: pair-sum rows {0,1} and {2,3}; lane parity selects row class
        float s01 = (b1 ? rs1 : rs0) + __shfl_xor(b1 ? rs0 : rs1, 1);
        float s23 = (b1 ? rs3 : rs2) + __shfl_xor(b1 ? rs2 : rs3, 1);
        // stage 2: fold the two classes; lane&3 == row index within the quad
        float s   = (b2 ? s23 : s01) + __shfl_xor(b2 ? s01 : s23, 2);
        s += __shfl_xor(s, 4);
        s += __shfl_xor(s, 8);
        s += __shfl_xor(s, 16);
        s += __shfl_xor(s, 32);
        if (lane < 4) lds_row[rbase + lane] = s;
    }
    ((float4*)lds_col)[w * 64 + lane] = make_float4(c0, c1, c2, c3);
    __syncthreads();
    const float cs = lds_col[tid] + lds_col[256 + tid]
                   + lds_col[512 + tid] + lds_col[768 + tid];
    const int oidx = bid * 256 + tid;
    ws[WS_HMAP + oidx] = cs * (1.f / 256.f);           // mean over p1 (rows)
    ws[WS_HMUE + oidx] = lds_row[tid] * (1.f / 256.f); // mean over p2 (cols)

    // A row means: rows 2*bid + w for w<2 (0..1023 = A_AP, 1024..2047 = A_UE)
    if (w < 2) {
        const int r = bid * 2 + w;
        const bool is_ap = (r < 1024);
        const float4* src = is_ap ? (const float4*)(A_AP + (size_t)r * 256)
                                  : (const float4*)(A_UE + (size_t)(r - 1024) * 256);
        const float4 vv = src[lane];
        float s = (vv.x + vv.y) + (vv.z + vv.w);
        s += __shfl_xor(s, 1);
        s += __shfl_xor(s, 2);
        s += __shfl_xor(s, 4);
        s += __shfl_xor(s, 8);
        s += __shfl_xor(s, 16);
        s += __shfl_xor(s, 32);
        if (lane == 0) {
            if (is_ap) ws[WS_APM + r] = s * (1.f / 256.f);
            else       ws[WS_UEM + (r - 1024)] = s * (1.f / 256.f);
        }
    }
}

// Kernel 2: z[g][b][o][p] = relu( 2*(sum_d Q1[o,d]A[b,d,p] + s2[b,o]) + 0.1*sum_d P1[o,d]hm[b,d,p] )
// 1024 blocks = (g, b, o-tile of 2); thread = p. 4 blocks/CU.
__global__ __launch_bounds__(256) void k_z(
    const float* __restrict__ A_AP, const float* __restrict__ A_UE,
    const float* __restrict__ Q1_AP, const float* __restrict__ Q2_AP,
    const float* __restrict__ Q1_UE, const float* __restrict__ Q2_UE,
    const float* __restrict__ P1_AP, const float* __restrict__ P1_UE,
    const float* __restrict__ ws)
{
    float* wsm = (float*)ws;
    const int bid = blockIdx.x;
    const int g   = bid >> 9;
    const int rem = bid & 511;
    const int b   = rem >> 5;
    const int o0  = (rem & 31) * 2;
    const int p   = threadIdx.x;
    const int w   = p >> 6;
    const int lane = p & 63;

    const float* A  = g ? A_UE : A_AP;
    const float* hm = ws + (g ? WS_HMAP : WS_HMUE);
    const float* am = ws + (g ? WS_APM  : WS_UEM);  // out_ap uses ue_mean; out_ue uses ap_mean
    const float* Q1 = g ? Q1_UE : Q1_AP;
    const float* Q2 = g ? Q2_UE : Q2_AP;
    const float* P1 = g ? P1_UE : P1_AP;

    __shared__ float s2[2];
    // waves 0,1 compute s2[w] = dot(Q2[o0+w], am[b]) via butterfly
    if (w < 2) {
        float pr = Q2[(o0 + w) * 64 + lane] * am[b * 64 + lane];
        pr += __shfl_xor(pr, 1);
        pr += __shfl_xor(pr, 2);
        pr += __shfl_xor(pr, 4);
        pr += __shfl_xor(pr, 8);
        pr += __shfl_xor(pr, 16);
        pr += __shfl_xor(pr, 32);
        if (lane == 0) s2[w] = pr;
    }
    __syncthreads();

    float accQ[2] = {0.f, 0.f};
    float accP[2] = {0.f, 0.f};
    const float* Ab = A  + (b << 14) + p;   // b*64*256
    const float* hb = hm + (b << 14) + p;

    #pragma unroll 4
    for (int dd = 0; dd < 16; ++dd) {
        const int d0 = dd * 4;
        float a0 = Ab[(d0 + 0) * 256];
        float a1 = Ab[(d0 + 1) * 256];
        float a2 = Ab[(d0 + 2) * 256];
        float a3 = Ab[(d0 + 3) * 256];
        float h0 = hb[(d0 + 0) * 256];
        float h1 = hb[(d0 + 1) * 256];
        float h2 = hb[(d0 + 2) * 256];
        float h3 = hb[(d0 + 3) * 256];
        #pragma unroll
        for (int j = 0; j < 2; ++j) {
            const float4 q  = *(const float4*)(Q1 + (o0 + j) * 64 + d0);
            const float4 pc = *(const float4*)(P1 + (o0 + j) * 64 + d0);
            accQ[j] += q.x * a0 + q.y * a1 + q.z * a2 + q.w * a3;
            accP[j] += pc.x * h0 + pc.y * h1 + pc.z * h2 + pc.w * h3;
        }
    }

    #pragma unroll
    for (int j = 0; j < 2; ++j) {
        float zv = 2.f * (accQ[j] + s2[j]) + 0.1f * accP[j];
        zv = fmaxf(zv, 0.f);
        wsm[WS_Z + ((size_t)(g * 16 + b) * 64 + (o0 + j)) * 256 + p] = zv;
    }
}

// Kernel 3: BatchNorm train-mode per channel o over (b,p): 4096 elems in registers.
__global__ __launch_bounds__(256) void k_bn(
    const float* __restrict__ z,
    const float* __restrict__ gamma, const float* __restrict__ beta,
    float* __restrict__ out)
{
    const int g = blockIdx.x >> 6;
    const int o = blockIdx.x & 63;
    const int t = threadIdx.x;
    const int w = t >> 6;
    const int lane = t & 63;

    const float* zp = z + (size_t)g * 262144 + o * 256 + t;  // b stride = 16384
    float v[16];
    float s = 0.f, q = 0.f;
    #pragma unroll
    for (int b = 0; b < 16; ++b) {
        float x = zp[b * 16384];
        v[b] = x;
        s += x;
        q += x * x;
    }
    #pragma unroll
    for (int m = 1; m <= 32; m <<= 1) {
        s += __shfl_xor(s, m);
        q += __shfl_xor(q, m);
    }
    __shared__ float ls[4], lq[4];
    if (lane == 0) { ls[w] = s; lq[w] = q; }
    __syncthreads();
    s = ls[0] + ls[1] + ls[2] + ls[3];
    q = lq[0] + lq[1] + lq[2] + lq[3];

    const float mean = s * (1.f / 4096.f);
    const float var  = q * (1.f / 4096.f) - mean * mean;
    const float rstd = rsqrtf(var + 1e-5f);
    const float scale = rstd * gamma[o];
    const float shift = beta[o] - mean * scale;

    float* op = out + (size_t)g * 262144 + o * 256 + t;
    #pragma unroll
    for (int b = 0; b < 16; ++b)
        op[b * 16384] = v[b] * scale + shift;
}

extern "C" void kernel_launch(void* const* d_in, const int* in_sizes, int n_in,
                              void* d_out, int out_size, void* d_ws, size_t ws_size,
                              hipStream_t stream)
{
    const float* A_AP  = (const float*)d_in[0];
    const float* A_UE  = (const float*)d_in[1];
    const float* H     = (const float*)d_in[2];
    const float* Q1_AP = (const float*)d_in[3];
    const float* Q2_AP = (const float*)d_in[4];
    const float* Q1_UE = (const float*)d_in[5];
    const float* Q2_UE = (const float*)d_in[6];
    const float* P1_AP = (const float*)d_in[7];
    const float* P1_UE = (const float*)d_in[8];
    const float* gamma = (const float*)d_in[9];
    const float* beta  = (const float*)d_in[10];

    float* ws  = (float*)d_ws;
    float* out = (float*)d_out;

    hipLaunchKernelGGL(k_reduce, dim3(1024), dim3(256), 0, stream,
                       H, A_AP, A_UE, ws);

    hipLaunchKernelGGL(k_z, dim3(1024), dim3(256), 0, stream,
                       A_AP, A_UE, Q1_AP, Q2_AP, Q1_UE, Q2_UE, P1_AP, P1_UE,
                       ws);

    hipLaunchKernelGGL(k_bn, dim3(128), dim3(256), 0, stream,
                       ws + WS_Z, gamma, beta, out);
}